// Round 1
// baseline (455.587 us; speedup 1.0000x reference)
//
#include <hip/hip_runtime.h>

// Problem constants (match reference)
constexpr int Bc   = 2;
constexpr int Nc   = 40000;
constexpr int CIN  = 64;     // input channels (= 64 lanes, one per channel)
constexpr int Mc   = 40000;
constexpr int Kc   = 16;     // neighbors
constexpr int Hc   = 8;      // guidance heads; head = c >> 3
constexpr int CMID = 16;     // weightnet dim

// One wave (64 lanes) per (b,m) point. Lane l owns output channel c = l,
// accumulating acc[d], d = 0..15 in registers. 4 waves per 256-thread block.
// LDS only used for the output transpose so global stores are coalesced.
// Padded stride 20 floats (80 B): 16B-aligned for b128 ops, low bank conflict.
__global__ __launch_bounds__(256, 4)
void pcf_fused(const float* __restrict__ feat,   // [B, N, 64]
               const int*   __restrict__ inds,   // [B, M, 16]
               const float* __restrict__ guid,   // [B, M, 16, 8]
               const float* __restrict__ wnet,   // [B, M, 16, 16]
               float*       __restrict__ out)    // [B, M, 1024]
{
    __shared__ float lds[4][64 * 20];

    const int lane = threadIdx.x & 63;
    // force wave-uniform so per-point pointers become SGPRs -> s_load for idx/wnet
    const int wave = __builtin_amdgcn_readfirstlane((int)(threadIdx.x >> 6));
    const int bm   = blockIdx.x * 4 + wave;          // 0 .. B*M-1
    const int b    = bm / Mc;

    const float* fp = feat + (size_t)b  * Nc * CIN;
    const int*   ip = inds + (size_t)bm * Kc;
    const float* gp = guid + (size_t)bm * Kc * Hc;
    const float* wp = wnet + (size_t)bm * Kc * CMID;
    float*       op = out  + (size_t)bm * CIN * CMID;

    float acc[CMID];
#pragma unroll
    for (int d = 0; d < CMID; ++d) acc[d] = 0.0f;

#pragma unroll
    for (int k = 0; k < Kc; ++k) {
        const int   nid = ip[k];                           // wave-uniform -> s_load
        const float f   = fp[(size_t)nid * CIN + lane];    // coalesced 256B row
        const float g   = gp[k * Hc + (lane >> 3)];        // 32B broadcast segment
        const float mod = f * g;
#pragma unroll
        for (int d = 0; d < CMID; ++d)
            acc[d] = fmaf(mod, wp[k * CMID + d], acc[d]);  // wnet uniform -> s_load
    }

    // ---- transpose acc through LDS so stores are coalesced ----
    // write: lane l -> rows [l][d], padded stride 20 floats
    float* wl = &lds[wave][0];
#pragma unroll
    for (int j = 0; j < 4; ++j) {
        float4 v = make_float4(acc[4 * j + 0], acc[4 * j + 1],
                               acc[4 * j + 2], acc[4 * j + 3]);
        *reinterpret_cast<float4*>(wl + lane * 20 + 4 * j) = v;  // 80B*l + 16B*j : aligned
    }
    __syncthreads();   // uniform; also orders intra-wave LDS write->read

    // read back: output element o = 256*jp + 4*lane + i  (i=0..3) -> c=o>>4, d=o&15
#pragma unroll
    for (int jp = 0; jp < 4; ++jp) {
        const int c0 = 16 * jp + (lane >> 2);
        const int d0 = (lane & 3) * 4;
        float4 v = *reinterpret_cast<const float4*>(wl + c0 * 20 + d0);
        *reinterpret_cast<float4*>(op + 256 * jp + 4 * lane) = v;  // 1KB coalesced/wave
    }
}

extern "C" void kernel_launch(void* const* d_in, const int* in_sizes, int n_in,
                              void* d_out, int out_size, void* d_ws, size_t ws_size,
                              hipStream_t stream) {
    const float* feat = (const float*)d_in[0];
    const int*   inds = (const int*)  d_in[1];
    const float* guid = (const float*)d_in[2];
    const float* wnet = (const float*)d_in[3];
    float*       out  = (float*)d_out;

    const int total_points = Bc * Mc;          // 80000
    const int blocks       = total_points / 4; // 4 waves/block, 1 point/wave
    pcf_fused<<<blocks, 256, 0, stream>>>(feat, inds, guid, wnet, out);
}